// Round 6
// baseline (342.525 us; speedup 1.0000x reference)
//
#include <hip/hip_runtime.h>
#include <hip/hip_bf16.h>
#include <stdint.h>

#define M_DIM 8192
#define N_DIM 4096   // OUT_F
#define K_DIM 4096   // IN_F

#define BM 256
#define BN 256
#define BK 32
#define NT (K_DIM / BK)   // 128 K-tiles

typedef __bf16 bf16_t;
typedef __attribute__((ext_vector_type(8))) __bf16 bf16x8;
typedef __attribute__((ext_vector_type(4))) float f32x4;

// ---------------- fp32 -> bf16 convert (vectorized, grid-stride) ----------------
__global__ void cvt_f32_to_bf16(const float* __restrict__ in, bf16_t* __restrict__ out, int n8) {
    int stride = gridDim.x * blockDim.x;
    for (int i = blockIdx.x * blockDim.x + threadIdx.x; i < n8; i += stride) {
        const float4* p = reinterpret_cast<const float4*>(in) + 2 * (size_t)i;
        float4 v0 = p[0];
        float4 v1 = p[1];
        bf16x8 o;
        o[0] = (bf16_t)v0.x; o[1] = (bf16_t)v0.y; o[2] = (bf16_t)v0.z; o[3] = (bf16_t)v0.w;
        o[4] = (bf16_t)v1.x; o[5] = (bf16_t)v1.y; o[6] = (bf16_t)v1.z; o[7] = (bf16_t)v1.w;
        *(reinterpret_cast<bf16x8*>(out) + (size_t)i) = o;
    }
}

// ---------------- 256x256 bf16 GEMM, m201-style phase template ----------------
// A: [M][K] bf16 row-major; B: [N][K] bf16 row-major (weight = B^T layout);
// C = A*B^T + bias, fp32 out.
//
// 3-deep LDS ring, stage lead 2 (tile T stages T+2). Per tile, 2 phases:
//  ph1: ds_read a0-3 (q0) + b0-3; stage A-halves(T+2); BAR; lgkm0; 16 MFMA; BAR
//  ph2: ds_read a4-7 (q1);        stage B-halves(T+2); vmcnt(4); BAR; lgkm0; 16 MFMA; BAR
// RAW (formal): at T ph2's vmcnt(4), issued-after tile T+1's last half = exactly
// T's 4 loads -> tile T+1 fully landed; published by ph2's closing barrier,
// one full tile before T+1 ph1 reads it. WAR: stage at T writes buf[(T+2)%3] =
// buf[(T-1)%3], whose reads finished before tile T-1's closing barrier.
// Epilogue tiles: T=126 uses vmcnt(0) (nothing issued after 127's halves),
// T=127 stages nothing.

#define MF(a, b, c) __builtin_amdgcn_mfma_f32_16x16x32_bf16((a), (b), (c), 0, 0, 0)
#define LD8(p) (*reinterpret_cast<const bf16x8*>(p))
#define GLL(src, dst) __builtin_amdgcn_global_load_lds(                               \
    (const __attribute__((address_space(1))) void*)(src),                             \
    (__attribute__((address_space(3))) void*)(dst), 16, 0, 0)

#define STAGE_A(T, BI) { const size_t ko_ = (size_t)(T) * BK;                         \
    GLL(gA0 + ko_, &Asm[BI][0][0] + dstv); GLL(gA1 + ko_, &Asm[BI][1][0] + dstv); }
#define STAGE_B(T, BI) { const size_t ko_ = (size_t)(T) * BK;                         \
    GLL(gB0 + ko_, &Bsm[BI][0][0] + dstv); GLL(gB1 + ko_, &Bsm[BI][1][0] + dstv); }

#define MM16(BASE, A0, A1, A2, A3)                                                    \
    acc[BASE+0][0]=MF(A0,b0_,acc[BASE+0][0]); acc[BASE+0][1]=MF(A0,b1_,acc[BASE+0][1]); \
    acc[BASE+0][2]=MF(A0,b2_,acc[BASE+0][2]); acc[BASE+0][3]=MF(A0,b3_,acc[BASE+0][3]); \
    acc[BASE+1][0]=MF(A1,b0_,acc[BASE+1][0]); acc[BASE+1][1]=MF(A1,b1_,acc[BASE+1][1]); \
    acc[BASE+1][2]=MF(A1,b2_,acc[BASE+1][2]); acc[BASE+1][3]=MF(A1,b3_,acc[BASE+1][3]); \
    acc[BASE+2][0]=MF(A2,b0_,acc[BASE+2][0]); acc[BASE+2][1]=MF(A2,b1_,acc[BASE+2][1]); \
    acc[BASE+2][2]=MF(A2,b2_,acc[BASE+2][2]); acc[BASE+2][3]=MF(A2,b3_,acc[BASE+2][3]); \
    acc[BASE+3][0]=MF(A3,b0_,acc[BASE+3][0]); acc[BASE+3][1]=MF(A3,b1_,acc[BASE+3][1]); \
    acc[BASE+3][2]=MF(A3,b2_,acc[BASE+3][2]); acc[BASE+3][3]=MF(A3,b3_,acc[BASE+3][3]);

#define TILE(T, CUR, STN, STG, VMSTR) do {                                            \
    bf16_t* Ab_ = &Asm[CUR][wm][0];                                                   \
    bf16_t* Bb_ = &Bsm[CUR][wnh][0];                                                  \
    /* ---- phase 1 (q0, 16 MFMA) ---- */                                             \
    bf16x8 a0_ = LD8(Ab_ + oa0), a1_ = LD8(Ab_ + oa1);                                \
    bf16x8 a2_ = LD8(Ab_ + oa2), a3_ = LD8(Ab_ + oa3);                                \
    bf16x8 b0_ = LD8(Bb_ + ob0), b1_ = LD8(Bb_ + ob1);                                \
    bf16x8 b2_ = LD8(Bb_ + ob2), b3_ = LD8(Bb_ + ob3);                                \
    if (STG) STAGE_A((T) + 2, STN);                                                   \
    __builtin_amdgcn_s_barrier();                                                     \
    asm volatile("s_waitcnt lgkmcnt(0)" ::: "memory");                                \
    __builtin_amdgcn_sched_barrier(0);                                                \
    __builtin_amdgcn_s_setprio(1);                                                    \
    MM16(0, a0_, a1_, a2_, a3_);                                                      \
    __builtin_amdgcn_s_setprio(0);                                                    \
    __builtin_amdgcn_s_barrier();                                                     \
    /* ---- phase 2 (q1, 16 MFMA) ---- */                                             \
    a0_ = LD8(Ab_ + oa4); a1_ = LD8(Ab_ + oa5);                                       \
    a2_ = LD8(Ab_ + oa6); a3_ = LD8(Ab_ + oa7);                                       \
    if (STG) STAGE_B((T) + 2, STN);                                                   \
    asm volatile(VMSTR ::: "memory");                                                 \
    __builtin_amdgcn_s_barrier();                                                     \
    asm volatile("s_waitcnt lgkmcnt(0)" ::: "memory");                                \
    __builtin_amdgcn_sched_barrier(0);                                                \
    __builtin_amdgcn_s_setprio(1);                                                    \
    MM16(4, a0_, a1_, a2_, a3_);                                                      \
    __builtin_amdgcn_s_setprio(0);                                                    \
    __builtin_amdgcn_s_barrier();                                                     \
} while (0)

__global__ __launch_bounds__(512, 2) void gemm_bf16_ph(
        const bf16_t* __restrict__ A, const bf16_t* __restrict__ B,
        const float* __restrict__ bias, float* __restrict__ C) {

    // 3 bufs x 2 halves x (128 rows x 32 bf16) for A and B: 96 KiB total
    __shared__ __align__(16) bf16_t Asm[3][2][128 * 32];
    __shared__ __align__(16) bf16_t Bsm[3][2][128 * 32];

    const int tid  = threadIdx.x;
    const int lane = tid & 63;
    const int wave = tid >> 6;        // 0..7
    const int wm   = wave >> 2;       // 0..1 : M half (128 rows) == A-half index
    const int wn   = wave & 3;        // 0..3 : N quarter (64 cols)
    const int wnl  = wn & 1;          // row-offset (x64) within B-half
    const int wnh  = wn >> 1;         // B-half index

    // XCD-aware swizzle (nwg = 512, divisible by 8 -> bijective)
    const int nwg = gridDim.x;
    const int cpx = nwg >> 3;
    const int swz = (blockIdx.x & 7) * cpx + (blockIdx.x >> 3);
    const int ntn = N_DIM / BN;       // 16
    const int brow = (swz / ntn) * BM;
    const int bcol = (swz % ntn) * BN;

    // ---- staging geometry: half = 128 rows x 32 bf16 = 8KB = 512 slots of 16B;
    // slot s holds (row = s>>2, chunk = (s&3) ^ ((row>>1)&3))  [r2-verified, 0 conflicts].
    // One global_load_lds per thread per half.
    const int slot = wave * 64 + lane;
    const int sr   = slot >> 2;                                   // 0..127
    const int scz  = (((slot & 3) ^ ((sr >> 1) & 3)) << 3);       // elems
    const bf16_t* gA0 = A + (size_t)(brow + sr) * K_DIM + scz;          // A half 0
    const bf16_t* gA1 = A + (size_t)(brow + 128 + sr) * K_DIM + scz;    // A half 1
    const bf16_t* gB0 = B + (size_t)(bcol + sr) * K_DIM + scz;          // B half 0
    const bf16_t* gB1 = B + (size_t)(bcol + 128 + sr) * K_DIM + scz;    // B half 1
    const int dstv = wave * 512;      // elem offset of wave's 64x16B stripe

    // ---- ds_read fragment offsets within a half (elems), swizzle-matched
    const int fr = lane & 15;
    const int cc = lane >> 4;         // k-chunk 0..3 (k = cc*8)
#define AOFFH(q, mi) ({ int lr_ = (q)*64 + (mi)*16 + fr;                              \
                        lr_*32 + ((cc ^ ((lr_ >> 1) & 3)) << 3); })
#define BOFFH(ni)    ({ int lr_ = wnl*64 + (ni)*16 + fr;                              \
                        lr_*32 + ((cc ^ ((lr_ >> 1) & 3)) << 3); })
    const int oa0 = AOFFH(0,0), oa1 = AOFFH(0,1), oa2 = AOFFH(0,2), oa3 = AOFFH(0,3);
    const int oa4 = AOFFH(1,0), oa5 = AOFFH(1,1), oa6 = AOFFH(1,2), oa7 = AOFFH(1,3);
    const int ob0 = BOFFH(0), ob1 = BOFFH(1), ob2 = BOFFH(2), ob3 = BOFFH(3);

    f32x4 acc[8][4];
#pragma unroll
    for (int i = 0; i < 8; i++)
#pragma unroll
        for (int j = 0; j < 4; j++)
            acc[i][j] = (f32x4){0.f, 0.f, 0.f, 0.f};

    // ---- prologue: stage tiles 0 and 1; land tile 0 (8 loads -> wait to 4)
    STAGE_A(0, 0) STAGE_B(0, 0)
    STAGE_A(1, 1) STAGE_B(1, 1)
    asm volatile("s_waitcnt vmcnt(4)" ::: "memory");
    __builtin_amdgcn_s_barrier();

    // ---- main loop: ring index cur = t%3, staging target stn = (t+2)%3
    int cur = 0, stn = 2;
    for (int t = 0; t < NT - 2; ++t) {
        TILE(t, cur, stn, 1, "s_waitcnt vmcnt(4)");
        cur = (cur == 2) ? 0 : cur + 1;
        stn = (stn == 2) ? 0 : stn + 1;
    }
    TILE(NT - 2, cur, stn, 0, "s_waitcnt vmcnt(0)");
    cur = (cur == 2) ? 0 : cur + 1;
    TILE(NT - 1, cur, 0, 0, "s_nop 0");

    // ---- epilogue: C/D layout col = lane&15, row = (lane>>4)*4 + r
    const int cc0 = bcol + wn * 64 + (lane & 15);
    const int rr0 = brow + wm * 128 + (lane >> 4) * 4;

    float bv[4];
#pragma unroll
    for (int ni = 0; ni < 4; ni++) bv[ni] = bias[cc0 + ni * 16];

#pragma unroll
    for (int p = 0; p < 2; p++) {
#pragma unroll
        for (int i = 0; i < 4; i++) {
#pragma unroll
            for (int r = 0; r < 4; r++) {
                const size_t row = (size_t)(rr0 + p * 64 + i * 16 + r);
#pragma unroll
                for (int ni = 0; ni < 4; ni++) {
                    C[row * N_DIM + cc0 + ni * 16] = acc[p * 4 + i][ni][r] + bv[ni];
                }
            }
        }
    }
}

// ---------------- safety-net fallback (no workspace): plain fp32 dot ----------------
__global__ void gemm_fallback_f32(const float* __restrict__ A, const float* __restrict__ B,
                                  const float* __restrict__ bias, float* __restrict__ C) {
    int n = blockIdx.x * 16 + threadIdx.x;
    int m = blockIdx.y * 16 + threadIdx.y;
    if (m >= M_DIM || n >= N_DIM) return;
    const float4* a = reinterpret_cast<const float4*>(A + (size_t)m * K_DIM);
    const float4* b = reinterpret_cast<const float4*>(B + (size_t)n * K_DIM);
    float s = 0.f;
    for (int k = 0; k < K_DIM / 4; k++) {
        float4 x = a[k], y = b[k];
        s += x.x * y.x + x.y * y.y + x.z * y.z + x.w * y.w;
    }
    C[(size_t)m * N_DIM + n] = s + bias[n];
}

extern "C" void kernel_launch(void* const* d_in, const int* in_sizes, int n_in,
                              void* d_out, int out_size, void* d_ws, size_t ws_size,
                              hipStream_t stream) {
    const float* x    = (const float*)d_in[0];   // [M][K] fp32
    const float* w    = (const float*)d_in[1];   // [N][K] fp32 (B^T layout)
    const float* bias = (const float*)d_in[2];   // [N] fp32
    float* out = (float*)d_out;

    const size_t xb = (size_t)M_DIM * K_DIM * sizeof(bf16_t);   // 64 MB
    const size_t wb = (size_t)N_DIM * K_DIM * sizeof(bf16_t);   // 32 MB

    if (ws_size >= xb + wb) {
        bf16_t* xbf = (bf16_t*)d_ws;
        bf16_t* wbf = (bf16_t*)((char*)d_ws + xb);

        cvt_f32_to_bf16<<<2048, 256, 0, stream>>>(x, xbf, (M_DIM * K_DIM) / 8);
        cvt_f32_to_bf16<<<1024, 256, 0, stream>>>(w, wbf, (N_DIM * K_DIM) / 8);

        const int grid = (M_DIM / BM) * (N_DIM / BN);   // 32 * 16 = 512
        gemm_bf16_ph<<<grid, 512, 0, stream>>>(xbf, wbf, bias, out);
    } else {
        dim3 block(16, 16);
        dim3 grid(N_DIM / 16, M_DIM / 16);
        gemm_fallback_f32<<<grid, block, 0, stream>>>(x, w, bias, out);
    }
}